// Round 2
// baseline (1455.048 us; speedup 1.0000x reference)
//
#include <hip/hip_runtime.h>

typedef __bf16 bf16x8 __attribute__((ext_vector_type(8)));
typedef float f32x4 __attribute__((ext_vector_type(4)));

#define FIN 512
#define FOUT 256

__device__ __forceinline__ float b2f(unsigned short u) {
  union { unsigned int u; float f; } x;
  x.u = ((unsigned int)u) << 16;
  return x.f;
}
__device__ __forceinline__ unsigned short f2b(float f) {
  union { float f; unsigned int u; } x; x.f = f;
  unsigned int u = x.u;
  unsigned int r = (u + 0x7fffu + ((u >> 16) & 1u)) >> 16;
  return (unsigned short)r;
}

// ---- dtype probe: flags[0]=1 iff X is float32; flags[1]=1 iff edge is int64.
// bf16 N(0,1) data never has exp-field 0xFF; f32 data read as ushorts has
// ~1/256 of low-half slots with exp 0xFF (uniform mantissa bits 14:7).
// int64 edge values in [0,1e5) have every odd int32 slot == 0.
__global__ void k_probe(const unsigned short* __restrict__ xh,
                        const int* __restrict__ e, int* __restrict__ flags) {
  __shared__ int cnt[2];
  if (threadIdx.x == 0) { cnt[0] = 0; cnt[1] = 0; }
  __syncthreads();
  int c = 0;
  for (int i = threadIdx.x; i < 32768; i += 256) {
    unsigned short u = xh[i];
    if (((u >> 7) & 0xFF) == 0xFF) c++;
  }
  if (c) atomicAdd(&cnt[0], c);
  if (e[2 * threadIdx.x + 1] == 0) atomicAdd(&cnt[1], 1);
  __syncthreads();
  if (threadIdx.x == 0) {
    flags[0] = (cnt[0] > 0) ? 1 : 0;
    flags[1] = (cnt[1] > 128) ? 1 : 0;
  }
}

// ---- Wt[n*512+k] = bf16(W[k*256+n])
__global__ void k_transpose(const void* __restrict__ W,
                            unsigned short* __restrict__ Wt,
                            const int* __restrict__ flags) {
  int idx = blockIdx.x * 256 + threadIdx.x;   // 0..131071
  int k = idx >> 8, n = idx & 255;
  float v = flags[0] ? ((const float*)W)[idx]
                     : b2f(((const unsigned short*)W)[idx]);
  Wt[n * FIN + k] = f2b(v);
}

// ---- H = bf16(X @ W + bias). BM=16, BN=256, no LDS: wave w does cols
// [64w,64w+64) of one 16-row tile; A/B fragments loaded straight from global.
__global__ __launch_bounds__(256) void k_gemm(const void* __restrict__ X,
                                              const unsigned short* __restrict__ Wt,
                                              const void* __restrict__ bias,
                                              unsigned short* __restrict__ H,
                                              int nrows, const int* __restrict__ flags) {
  const int tid = threadIdx.x;
  const int wave = tid >> 6;
  const int lane = tid & 63;
  const int fm = lane & 15;     // m (A) / n (B) / col (C)
  const int fq = lane >> 4;     // quad
  const int isf = flags[0];
  int arow = blockIdx.x * 16 + fm;
  bool valid = arow < nrows;
  if (!valid) arow = nrows - 1;

  f32x4 acc[4];
#pragma unroll
  for (int i = 0; i < 4; i++) acc[i] = (f32x4){0.f, 0.f, 0.f, 0.f};

  const unsigned short* wp[4];
#pragma unroll
  for (int i = 0; i < 4; i++)
    wp[i] = Wt + (size_t)((wave * 4 + i) * 16 + fm) * FIN + fq * 8;

  if (isf) {
    const float* xp = (const float*)X + (size_t)arow * FIN + fq * 8;
    for (int k0 = 0; k0 < FIN; k0 += 32) {
      f32x4 lo = *(const f32x4*)(xp + k0);
      f32x4 hi = *(const f32x4*)(xp + k0 + 4);
      union { bf16x8 v; unsigned short u[8]; } cv;
#pragma unroll
      for (int j = 0; j < 4; j++) { cv.u[j] = f2b(lo[j]); cv.u[4 + j] = f2b(hi[j]); }
      bf16x8 af = cv.v;
#pragma unroll
      for (int i = 0; i < 4; i++) {
        bf16x8 bfr = *(const bf16x8*)(wp[i] + k0);
        acc[i] = __builtin_amdgcn_mfma_f32_16x16x32_bf16(af, bfr, acc[i], 0, 0, 0);
      }
    }
  } else {
    const unsigned short* xp = (const unsigned short*)X + (size_t)arow * FIN + fq * 8;
    for (int k0 = 0; k0 < FIN; k0 += 32) {
      bf16x8 af = *(const bf16x8*)(xp + k0);
#pragma unroll
      for (int i = 0; i < 4; i++) {
        bf16x8 bfr = *(const bf16x8*)(wp[i] + k0);
        acc[i] = __builtin_amdgcn_mfma_f32_16x16x32_bf16(af, bfr, acc[i], 0, 0, 0);
      }
    }
  }

#pragma unroll
  for (int i = 0; i < 4; i++) {
    int col = (wave * 4 + i) * 16 + fm;
    float bv = isf ? ((const float*)bias)[col] : b2f(((const unsigned short*)bias)[col]);
#pragma unroll
    for (int r = 0; r < 4; r++) {
      int row = blockIdx.x * 16 + fq * 4 + r;   // C/D: col=lane&15, row=quad*4+reg
      if (row < nrows) H[(size_t)row * FOUT + col] = f2b(acc[i][r] + bv);
    }
  }
}

// ---- s1 = h@a_src, s2 = h@a_dst (fp32). One wave per row.
__global__ __launch_bounds__(256) void k_scores(const unsigned short* __restrict__ H,
                                                const void* __restrict__ a,
                                                float* __restrict__ s1, float* __restrict__ s2,
                                                int n, const int* __restrict__ flags) {
  int wave = threadIdx.x >> 6, lane = threadIdx.x & 63;
  int row = blockIdx.x * 4 + wave;
  if (row >= n) return;
  const ushort4* hp = (const ushort4*)(H + (size_t)row * FOUT);
  ushort4 hv = hp[lane];
  float as0, as1, as2, as3, ad0, ad1, ad2, ad3;
  if (flags[0]) {
    const float* af = (const float*)a;
    f32x4 s = *(const f32x4*)(af + lane * 4);
    f32x4 d = *(const f32x4*)(af + FOUT + lane * 4);
    as0 = s[0]; as1 = s[1]; as2 = s[2]; as3 = s[3];
    ad0 = d[0]; ad1 = d[1]; ad2 = d[2]; ad3 = d[3];
  } else {
    const ushort4* ap = (const ushort4*)a;
    ushort4 s = ap[lane], d = ap[64 + lane];
    as0 = b2f(s.x); as1 = b2f(s.y); as2 = b2f(s.z); as3 = b2f(s.w);
    ad0 = b2f(d.x); ad1 = b2f(d.y); ad2 = b2f(d.z); ad3 = b2f(d.w);
  }
  float h0 = b2f(hv.x), h1 = b2f(hv.y), h2 = b2f(hv.z), h3 = b2f(hv.w);
  float p1 = h0 * as0 + h1 * as1 + h2 * as2 + h3 * as3;
  float p2 = h0 * ad0 + h1 * ad1 + h2 * ad2 + h3 * ad3;
#pragma unroll
  for (int off = 32; off >= 1; off >>= 1) {
    p1 += __shfl_down(p1, off, 64);
    p2 += __shfl_down(p2, off, 64);
  }
  if (lane == 0) { s1[row] = p1; s2[row] = p2; }
}

__global__ void k_degree(const int* __restrict__ e, int* __restrict__ deg, int E,
                         const int* __restrict__ flags) {
  int i = blockIdx.x * 256 + threadIdx.x;
  if (i < E) {
    int s = flags[1] ? e[2 * i] : e[i];
    atomicAdd(&deg[s], 1);
  }
}

// single-block exclusive scan over deg -> rowptr (+ cursor copy)
__global__ __launch_bounds__(1024) void k_scan(const int* __restrict__ deg,
                                               int* __restrict__ rowptr,
                                               int* __restrict__ cursor, int n) {
  __shared__ int sums[1024];
  int t = threadIdx.x;
  int chunk = (n + 1023) / 1024;
  int lo = t * chunk; if (lo > n) lo = n;
  int hi = lo + chunk; if (hi > n) hi = n;
  int s = 0;
  for (int i = lo; i < hi; ++i) s += deg[i];
  sums[t] = s;
  __syncthreads();
  for (int off = 1; off < 1024; off <<= 1) {
    int v = (t >= off) ? sums[t - off] : 0;
    __syncthreads();
    sums[t] += v;
    __syncthreads();
  }
  int run = (t == 0) ? 0 : sums[t - 1];
  for (int i = lo; i < hi; ++i) {
    rowptr[i] = run; cursor[i] = run; run += deg[i];
  }
  if (t == 0) rowptr[n] = sums[1023];
}

__global__ void k_scatter(const int* __restrict__ e, int* __restrict__ cursor,
                          int* __restrict__ csrd, int E, const int* __restrict__ flags) {
  int i = blockIdx.x * 256 + threadIdx.x;
  if (i < E) {
    int s, d;
    if (flags[1]) { s = e[2 * i]; d = e[2 * (size_t)E + 2 * i]; }
    else          { s = e[i];     d = e[E + i]; }
    int pos = atomicAdd(&cursor[s], 1);
    csrd[pos] = d;
  }
}

// ---- per-src-node gather: h'[i] = sum_e w_e h[dst_e] / (sum w_e + EPS); out = elu
__global__ __launch_bounds__(256) void k_gather(const unsigned short* __restrict__ H,
                                                const float* __restrict__ s1,
                                                const float* __restrict__ s2,
                                                const int* __restrict__ rowptr,
                                                const int* __restrict__ csrd,
                                                void* __restrict__ out, int n,
                                                const int* __restrict__ flags) {
  int wave = threadIdx.x >> 6, lane = threadIdx.x & 63;
  int row = blockIdx.x * 4 + wave;
  if (row >= n) return;
  int isf = flags[0];
  int beg = rowptr[row], end = rowptr[row + 1];
  float s1v = s1[row];
  float a0 = 0.f, a1 = 0.f, a2 = 0.f, a3 = 0.f, wsum = 0.f;
  int e = beg;
  for (; e + 2 <= end; e += 2) {           // unroll-2: two independent load chains
    int d0 = csrd[e], d1 = csrd[e + 1];
    float v0 = s1v + s2[d0], v1 = s1v + s2[d1];
    v0 = v0 > 0.f ? v0 : 0.2f * v0;
    v1 = v1 > 0.f ? v1 : 0.2f * v1;
    float w0 = __expf(v0), w1 = __expf(v1);
    ushort4 h0 = *(const ushort4*)(H + (size_t)d0 * FOUT + lane * 4);
    ushort4 h1 = *(const ushort4*)(H + (size_t)d1 * FOUT + lane * 4);
    wsum += w0 + w1;
    a0 += w0 * b2f(h0.x) + w1 * b2f(h1.x);
    a1 += w0 * b2f(h0.y) + w1 * b2f(h1.y);
    a2 += w0 * b2f(h0.z) + w1 * b2f(h1.z);
    a3 += w0 * b2f(h0.w) + w1 * b2f(h1.w);
  }
  if (e < end) {
    int d0 = csrd[e];
    float v0 = s1v + s2[d0];
    v0 = v0 > 0.f ? v0 : 0.2f * v0;
    float w0 = __expf(v0);
    ushort4 h0 = *(const ushort4*)(H + (size_t)d0 * FOUT + lane * 4);
    wsum += w0;
    a0 += w0 * b2f(h0.x); a1 += w0 * b2f(h0.y);
    a2 += w0 * b2f(h0.z); a3 += w0 * b2f(h0.w);
  }
  float inv = 1.f / (wsum + 9e-15f);
  float o0 = a0 * inv, o1 = a1 * inv, o2 = a2 * inv, o3 = a3 * inv;
  o0 = o0 > 0.f ? o0 : __expf(o0) - 1.f;
  o1 = o1 > 0.f ? o1 : __expf(o1) - 1.f;
  o2 = o2 > 0.f ? o2 : __expf(o2) - 1.f;
  o3 = o3 > 0.f ? o3 : __expf(o3) - 1.f;
  if (isf) {
    f32x4 ov = {o0, o1, o2, o3};
    *(f32x4*)((float*)out + (size_t)row * FOUT + lane * 4) = ov;
  } else {
    ushort4 ov = { f2b(o0), f2b(o1), f2b(o2), f2b(o3) };
    *(ushort4*)((unsigned short*)out + (size_t)row * FOUT + lane * 4) = ov;
  }
}

extern "C" void kernel_launch(void* const* d_in, const int* in_sizes, int n_in,
                              void* d_out, int out_size, void* d_ws, size_t ws_size,
                              hipStream_t stream) {
  const void* X = d_in[0];
  const int* edge = (const int*)d_in[1];
  const void* W = d_in[2];
  const void* A = d_in[3];
  const void* B = d_in[4];
  int N_ = in_sizes[0] / FIN;     // 100000
  int E_ = in_sizes[1] / 2;       // 3200000

  char* p = (char*)d_ws;
  auto alloc = [&](size_t bytes) {
    char* r = p; p += (bytes + 255) & ~(size_t)255; return r;
  };
  int* flags = (int*)alloc(256);
  unsigned short* H  = (unsigned short*)alloc((size_t)N_ * FOUT * 2);
  unsigned short* Wt = (unsigned short*)alloc((size_t)FIN * FOUT * 2);
  float* s1   = (float*)alloc((size_t)N_ * 4);
  float* s2   = (float*)alloc((size_t)N_ * 4);
  int* deg    = (int*)alloc((size_t)N_ * 4);
  int* rowptr = (int*)alloc((size_t)(N_ + 1) * 4);
  int* cursor = (int*)alloc((size_t)N_ * 4);
  int* csrd   = (int*)alloc((size_t)E_ * 4);

  hipMemsetAsync(deg, 0, (size_t)N_ * 4, stream);
  k_probe<<<1, 256, 0, stream>>>((const unsigned short*)X, edge, flags);
  k_transpose<<<(FIN * FOUT) / 256, 256, 0, stream>>>(W, Wt, flags);
  k_gemm<<<(N_ + 15) / 16, 256, 0, stream>>>(X, Wt, B, H, N_, flags);
  k_scores<<<(N_ + 3) / 4, 256, 0, stream>>>(H, A, s1, s2, N_, flags);
  k_degree<<<(E_ + 255) / 256, 256, 0, stream>>>(edge, deg, E_, flags);
  k_scan<<<1, 1024, 0, stream>>>(deg, rowptr, cursor, N_);
  k_scatter<<<(E_ + 255) / 256, 256, 0, stream>>>(edge, cursor, csrd, E_, flags);
  k_gather<<<(N_ + 3) / 4, 256, 0, stream>>>(H, s1, s2, rowptr, csrd,
                                             d_out, N_, flags);
}

// Round 3
// 1081.106 us; speedup vs baseline: 1.3459x; 1.3459x over previous
//
#include <hip/hip_runtime.h>

typedef __bf16 bf16x8 __attribute__((ext_vector_type(8)));
typedef float f32x4 __attribute__((ext_vector_type(4)));
typedef unsigned short u16x8 __attribute__((ext_vector_type(8)));

#define FIN 512
#define FOUT 256

__device__ __forceinline__ float b2f(unsigned short u) {
  union { unsigned int u; float f; } x;
  x.u = ((unsigned int)u) << 16;
  return x.f;
}
__device__ __forceinline__ unsigned short f2b(float f) {
  union { float f; unsigned int u; } x; x.f = f;
  unsigned int u = x.u;
  unsigned int r = (u + 0x7fffu + ((u >> 16) & 1u)) >> 16;
  return (unsigned short)r;
}

// ---- dtype probe: flags[0]=1 iff X is float32; flags[1]=1 iff edge is int64.
__global__ void k_probe(const unsigned short* __restrict__ xh,
                        const int* __restrict__ e, int* __restrict__ flags) {
  __shared__ int cnt[2];
  if (threadIdx.x == 0) { cnt[0] = 0; cnt[1] = 0; }
  __syncthreads();
  int c = 0;
  for (int i = threadIdx.x; i < 32768; i += 256) {
    unsigned short u = xh[i];
    if (((u >> 7) & 0xFF) == 0xFF) c++;
  }
  if (c) atomicAdd(&cnt[0], c);
  if (e[2 * threadIdx.x + 1] == 0) atomicAdd(&cnt[1], 1);
  __syncthreads();
  if (threadIdx.x == 0) {
    flags[0] = (cnt[0] > 0) ? 1 : 0;
    flags[1] = (cnt[1] > 128) ? 1 : 0;
  }
}

// ---- Wt[n*512+k] = bf16(W[k*256+n])
__global__ void k_transpose(const void* __restrict__ W,
                            unsigned short* __restrict__ Wt,
                            const int* __restrict__ flags) {
  int idx = blockIdx.x * 256 + threadIdx.x;
  int k = idx >> 8, n = idx & 255;
  float v = flags[0] ? ((const float*)W)[idx]
                     : b2f(((const unsigned short*)W)[idx]);
  Wt[n * FIN + k] = f2b(v);
}

// ---- H = bf16(X @ W + bias). BM=64, BN=256, whole-K A-tile in LDS.
// A: 64 rows x 1KB, row r at lds+r*1024; slot p of row r holds true chunk
// p^(r%8) (XOR applied on the GLOBAL chunk index so the DMA dest is
// lane-linear and fragment ds_read_b128 is bank-uniform).
__global__ __launch_bounds__(256) void k_gemm(const void* __restrict__ X,
                                              const unsigned short* __restrict__ Wt,
                                              const void* __restrict__ bias,
                                              unsigned short* __restrict__ H,
                                              int nrows, const int* __restrict__ flags) {
  __shared__ char lds[65536];
  const int tid = threadIdx.x;
  const int wave = tid >> 6;
  const int lane = tid & 63;
  const int fm = lane & 15;     // m (A) / n (B) / col (C)
  const int fq = lane >> 4;     // quad
  const int isf = flags[0];
  const int m0 = blockIdx.x * 64;

  if (isf) {
    // f32 input: load+convert through VGPRs, ds_write lane-linear.
#pragma unroll 4
    for (int j = 0; j < 16; ++j) {
      int r = wave * 16 + j;
      int grow = m0 + r; if (grow >= nrows) grow = nrows - 1;
      int c = lane ^ (j & 7);
      const float* gp = (const float*)X + (size_t)grow * FIN + c * 8;
      f32x4 lo = *(const f32x4*)gp;
      f32x4 hi = *(const f32x4*)(gp + 4);
      union { bf16x8 v; unsigned short u[8]; } cv;
#pragma unroll
      for (int k = 0; k < 4; k++) { cv.u[k] = f2b(lo[k]); cv.u[4 + k] = f2b(hi[k]); }
      *(bf16x8*)(lds + r * 1024 + lane * 16) = cv.v;
    }
  } else {
    // bf16 input: async DMA, one contiguous 1KB row per instruction.
#pragma unroll
    for (int j = 0; j < 16; ++j) {
      int r = wave * 16 + j;
      int grow = m0 + r; if (grow >= nrows) grow = nrows - 1;
      int c = lane ^ (j & 7);
      const unsigned short* gp = (const unsigned short*)X + (size_t)grow * FIN + c * 8;
      __builtin_amdgcn_global_load_lds(
          (const __attribute__((address_space(1))) void*)gp,
          (__attribute__((address_space(3))) void*)(lds + r * 1024), 16, 0, 0);
    }
  }
  __syncthreads();

  f32x4 acc[4][4];
#pragma unroll
  for (int i = 0; i < 4; i++)
#pragma unroll
    for (int j = 0; j < 4; j++) acc[i][j] = (f32x4){0.f, 0.f, 0.f, 0.f};

  const unsigned short* wp[4];
#pragma unroll
  for (int i = 0; i < 4; i++)
    wp[i] = Wt + (size_t)((wave * 4 + i) * 16 + fm) * FIN + fq * 8;

  const int swz = fm & 7;
  bf16x8 bcur[4];
#pragma unroll
  for (int i = 0; i < 4; i++) bcur[i] = *(const bf16x8*)(wp[i]);

  for (int it = 0; it < 16; ++it) {
    int itn = (it + 1 < 16) ? it + 1 : 15;
    bf16x8 bnext[4];
#pragma unroll
    for (int i = 0; i < 4; i++) bnext[i] = *(const bf16x8*)(wp[i] + itn * 32);
    bf16x8 af[4];
#pragma unroll
    for (int mt = 0; mt < 4; mt++) {
      int slot = (it * 4 + fq) ^ swz;
      af[mt] = *(const bf16x8*)(lds + (mt * 16 + fm) * 1024 + slot * 16);
    }
#pragma unroll
    for (int mt = 0; mt < 4; mt++)
#pragma unroll
      for (int i = 0; i < 4; i++)
        acc[mt][i] = __builtin_amdgcn_mfma_f32_16x16x32_bf16(af[mt], bcur[i], acc[mt][i], 0, 0, 0);
#pragma unroll
    for (int i = 0; i < 4; i++) bcur[i] = bnext[i];
  }

#pragma unroll
  for (int i = 0; i < 4; i++) {
    int col = (wave * 4 + i) * 16 + fm;
    float bv = isf ? ((const float*)bias)[col] : b2f(((const unsigned short*)bias)[col]);
#pragma unroll
    for (int mt = 0; mt < 4; mt++) {
#pragma unroll
      for (int r = 0; r < 4; r++) {
        int row = m0 + mt * 16 + fq * 4 + r;   // C/D: col=lane&15, row=quad*4+reg
        if (row < nrows) H[(size_t)row * FOUT + col] = f2b(acc[mt][i][r] + bv);
      }
    }
  }
}

// ---- s1 = h@a_src, s2 = h@a_dst (fp32). One wave per row.
__global__ __launch_bounds__(256) void k_scores(const unsigned short* __restrict__ H,
                                                const void* __restrict__ a,
                                                float* __restrict__ s1, float* __restrict__ s2,
                                                int n, const int* __restrict__ flags) {
  int wave = threadIdx.x >> 6, lane = threadIdx.x & 63;
  int row = blockIdx.x * 4 + wave;
  if (row >= n) return;
  const ushort4* hp = (const ushort4*)(H + (size_t)row * FOUT);
  ushort4 hv = hp[lane];
  float as0, as1, as2, as3, ad0, ad1, ad2, ad3;
  if (flags[0]) {
    const float* af = (const float*)a;
    f32x4 s = *(const f32x4*)(af + lane * 4);
    f32x4 d = *(const f32x4*)(af + FOUT + lane * 4);
    as0 = s[0]; as1 = s[1]; as2 = s[2]; as3 = s[3];
    ad0 = d[0]; ad1 = d[1]; ad2 = d[2]; ad3 = d[3];
  } else {
    const ushort4* ap = (const ushort4*)a;
    ushort4 s = ap[lane], d = ap[64 + lane];
    as0 = b2f(s.x); as1 = b2f(s.y); as2 = b2f(s.z); as3 = b2f(s.w);
    ad0 = b2f(d.x); ad1 = b2f(d.y); ad2 = b2f(d.z); ad3 = b2f(d.w);
  }
  float h0 = b2f(hv.x), h1 = b2f(hv.y), h2 = b2f(hv.z), h3 = b2f(hv.w);
  float p1 = h0 * as0 + h1 * as1 + h2 * as2 + h3 * as3;
  float p2 = h0 * ad0 + h1 * ad1 + h2 * ad2 + h3 * ad3;
#pragma unroll
  for (int off = 32; off >= 1; off >>= 1) {
    p1 += __shfl_down(p1, off, 64);
    p2 += __shfl_down(p2, off, 64);
  }
  if (lane == 0) { s1[row] = p1; s2[row] = p2; }
}

__global__ void k_degree(const int* __restrict__ e, int* __restrict__ deg, int E,
                         const int* __restrict__ flags) {
  int i = blockIdx.x * 256 + threadIdx.x;
  if (i < E) {
    int s = flags[1] ? ((const int2*)e)[i].x : e[i];
    atomicAdd(&deg[s], 1);
  }
}

// ---- 3-phase coalesced scan: block partials -> scan partials -> add
__global__ __launch_bounds__(256) void k_scan_part(const int* __restrict__ deg,
                                                   int* __restrict__ bsum, int n) {
  __shared__ int ws[4];
  int t = threadIdx.x, i = blockIdx.x * 256 + t;
  int s = (i < n) ? deg[i] : 0;
#pragma unroll
  for (int off = 32; off >= 1; off >>= 1) s += __shfl_down(s, off, 64);
  if ((t & 63) == 0) ws[t >> 6] = s;
  __syncthreads();
  if (t == 0) bsum[blockIdx.x] = ws[0] + ws[1] + ws[2] + ws[3];
}

__global__ __launch_bounds__(512) void k_scan_mid(int* __restrict__ bsum, int nb) {
  __shared__ int sh[512];
  int t = threadIdx.x;
  int v = (t < nb) ? bsum[t] : 0;
  sh[t] = v;
  __syncthreads();
  for (int off = 1; off < 512; off <<= 1) {
    int u = (t >= off) ? sh[t - off] : 0;
    __syncthreads();
    sh[t] += u;
    __syncthreads();
  }
  if (t < nb) bsum[t] = sh[t] - v;   // exclusive
}

__global__ __launch_bounds__(256) void k_scan_add(const int* __restrict__ deg,
                                                  const int* __restrict__ bsum,
                                                  int* __restrict__ rowptr,
                                                  int* __restrict__ cursor, int n) {
  __shared__ int sh[256];
  int t = threadIdx.x, i = blockIdx.x * 256 + t;
  int v = (i < n) ? deg[i] : 0;
  sh[t] = v;
  __syncthreads();
  for (int off = 1; off < 256; off <<= 1) {
    int u = (t >= off) ? sh[t - off] : 0;
    __syncthreads();
    sh[t] += u;
    __syncthreads();
  }
  int excl = sh[t] - v + bsum[blockIdx.x];
  if (i < n) {
    rowptr[i] = excl; cursor[i] = excl;
    if (i == n - 1) rowptr[n] = excl + v;
  }
}

__global__ void k_scatter(const int* __restrict__ e, int* __restrict__ cursor,
                          int* __restrict__ csrd, int E, const int* __restrict__ flags) {
  int i = blockIdx.x * 256 + threadIdx.x;
  if (i < E) {
    int s, d;
    if (flags[1]) { s = ((const int2*)e)[i].x; d = ((const int2*)e)[(size_t)E + i].x; }
    else          { s = e[i];                  d = e[E + i]; }
    int pos = atomicAdd(&cursor[s], 1);
    csrd[pos] = d;
  }
}

// ---- per-src-node gather. Half-wave pairing: lanes [0,32) handle edge e,
// lanes [32,64) edge e+1; each lane covers 8 cols (16B of the H row).
__global__ __launch_bounds__(256) void k_gather(const unsigned short* __restrict__ H,
                                                const float* __restrict__ s1,
                                                const float* __restrict__ s2,
                                                const int* __restrict__ rowptr,
                                                const int* __restrict__ csrd,
                                                void* __restrict__ out, int n,
                                                const int* __restrict__ flags) {
  int wave = threadIdx.x >> 6, lane = threadIdx.x & 63;
  int row = blockIdx.x * 4 + wave;
  if (row >= n) return;
  int half = lane >> 5;          // which edge of the pair
  int hl = lane & 31;            // covers cols [8*hl, 8*hl+8)
  int beg = rowptr[row], end = rowptr[row + 1];
  float s1v = s1[row];
  float ac[8];
#pragma unroll
  for (int k = 0; k < 8; k++) ac[k] = 0.f;
  float wsum = 0.f;

#pragma unroll 2
  for (int e = beg; e < end; e += 2) {
    int ei = e + half;
    int ee = (ei < end) ? ei : beg;        // safe dup (beg<end here)
    int d = csrd[ee];
    float v = s1v + s2[d];
    v = v > 0.f ? v : 0.2f * v;
    float w = __expf(v);
    if (ei >= end) w = 0.f;
    union { u16x8 v; unsigned short u[8]; } hv;
    hv.v = *(const u16x8*)(H + (size_t)d * FOUT + hl * 8);
    wsum += w;
#pragma unroll
    for (int k = 0; k < 8; k++) ac[k] += w * b2f(hv.u[k]);
  }

  // combine the two halves: lanes [0,32) pull partner lane+32
#pragma unroll
  for (int k = 0; k < 8; k++) ac[k] += __shfl_down(ac[k], 32, 64);
  wsum += __shfl_down(wsum, 32, 64);

  if (half == 0) {
    float inv = 1.f / (wsum + 9e-15f);
    float o[8];
#pragma unroll
    for (int k = 0; k < 8; k++) {
      float x = ac[k] * inv;
      o[k] = x > 0.f ? x : __expf(x) - 1.f;
    }
    if (flags[0]) {
      float* op = (float*)out + (size_t)row * FOUT + hl * 8;
      *(f32x4*)op = (f32x4){o[0], o[1], o[2], o[3]};
      *(f32x4*)(op + 4) = (f32x4){o[4], o[5], o[6], o[7]};
    } else {
      union { u16x8 v; unsigned short u[8]; } ov;
#pragma unroll
      for (int k = 0; k < 8; k++) ov.u[k] = f2b(o[k]);
      *(u16x8*)((unsigned short*)out + (size_t)row * FOUT + hl * 8) = ov.v;
    }
  }
}

extern "C" void kernel_launch(void* const* d_in, const int* in_sizes, int n_in,
                              void* d_out, int out_size, void* d_ws, size_t ws_size,
                              hipStream_t stream) {
  const void* X = d_in[0];
  const int* edge = (const int*)d_in[1];
  const void* W = d_in[2];
  const void* A = d_in[3];
  const void* B = d_in[4];
  int N_ = in_sizes[0] / FIN;     // 100000
  int E_ = in_sizes[1] / 2;       // 3200000

  char* p = (char*)d_ws;
  auto alloc = [&](size_t bytes) {
    char* r = p; p += (bytes + 255) & ~(size_t)255; return r;
  };
  int* flags = (int*)alloc(256);
  unsigned short* H  = (unsigned short*)alloc((size_t)N_ * FOUT * 2);
  unsigned short* Wt = (unsigned short*)alloc((size_t)FIN * FOUT * 2);
  float* s1   = (float*)alloc((size_t)N_ * 4);
  float* s2   = (float*)alloc((size_t)N_ * 4);
  int* deg    = (int*)alloc((size_t)N_ * 4);
  int* rowptr = (int*)alloc((size_t)(N_ + 1) * 4);
  int* cursor = (int*)alloc((size_t)N_ * 4);
  int* csrd   = (int*)alloc((size_t)E_ * 4);
  int nb = (N_ + 255) / 256;
  int* bsum   = (int*)alloc((size_t)nb * 4);

  hipMemsetAsync(deg, 0, (size_t)N_ * 4, stream);
  k_probe<<<1, 256, 0, stream>>>((const unsigned short*)X, edge, flags);
  k_transpose<<<(FIN * FOUT) / 256, 256, 0, stream>>>(W, Wt, flags);
  k_gemm<<<(N_ + 63) / 64, 256, 0, stream>>>(X, Wt, B, H, N_, flags);
  k_scores<<<(N_ + 3) / 4, 256, 0, stream>>>(H, A, s1, s2, N_, flags);
  k_degree<<<(E_ + 255) / 256, 256, 0, stream>>>(edge, deg, E_, flags);
  k_scan_part<<<nb, 256, 0, stream>>>(deg, bsum, N_);
  k_scan_mid<<<1, 512, 0, stream>>>(bsum, nb);
  k_scan_add<<<nb, 256, 0, stream>>>(deg, bsum, rowptr, cursor, N_);
  k_scatter<<<(E_ + 255) / 256, 256, 0, stream>>>(edge, cursor, csrd, E_, flags);
  k_gather<<<(N_ + 3) / 4, 256, 0, stream>>>(H, s1, s2, rowptr, csrd,
                                             d_out, N_, flags);
}

// Round 4
// 774.501 us; speedup vs baseline: 1.8787x; 1.3959x over previous
//
#include <hip/hip_runtime.h>

typedef __bf16 bf16x8 __attribute__((ext_vector_type(8)));
typedef float f32x4 __attribute__((ext_vector_type(4)));
typedef unsigned short u16x8 __attribute__((ext_vector_type(8)));

#define FIN 512
#define FOUT 256
#define NBLK 256          // blocks for bcount/bscatter
#define BSHIFT 8          // bucket = 256 consecutive src nodes

__device__ __forceinline__ float b2f(unsigned short u) {
  union { unsigned int u; float f; } x;
  x.u = ((unsigned int)u) << 16;
  return x.f;
}
__device__ __forceinline__ unsigned short f2b(float f) {
  union { float f; unsigned int u; } x; x.f = f;
  unsigned int u = x.u;
  unsigned int r = (u + 0x7fffu + ((u >> 16) & 1u)) >> 16;
  return (unsigned short)r;
}

// ---- dtype probe: flags[0]=1 iff X is float32; flags[1]=1 iff edge is int64.
__global__ void k_probe(const unsigned short* __restrict__ xh,
                        const int* __restrict__ e, int* __restrict__ flags) {
  __shared__ int cnt[2];
  if (threadIdx.x == 0) { cnt[0] = 0; cnt[1] = 0; }
  __syncthreads();
  int c = 0;
  for (int i = threadIdx.x; i < 32768; i += 256) {
    unsigned short u = xh[i];
    if (((u >> 7) & 0xFF) == 0xFF) c++;
  }
  if (c) atomicAdd(&cnt[0], c);
  if (e[2 * threadIdx.x + 1] == 0) atomicAdd(&cnt[1], 1);
  __syncthreads();
  if (threadIdx.x == 0) {
    flags[0] = (cnt[0] > 0) ? 1 : 0;
    flags[1] = (cnt[1] > 128) ? 1 : 0;
  }
}

// ---- Wt[n*512+k] = bf16(W[k*256+n])
__global__ void k_transpose(const void* __restrict__ W,
                            unsigned short* __restrict__ Wt,
                            const int* __restrict__ flags) {
  int idx = blockIdx.x * 256 + threadIdx.x;
  int k = idx >> 8, n = idx & 255;
  float v = flags[0] ? ((const float*)W)[idx]
                     : b2f(((const unsigned short*)W)[idx]);
  Wt[n * FIN + k] = f2b(v);
}

// ---- H = bf16(X @ W + bias). BM=64, BN=256, whole-K A-tile in LDS.
__global__ __launch_bounds__(256) void k_gemm(const void* __restrict__ X,
                                              const unsigned short* __restrict__ Wt,
                                              const void* __restrict__ bias,
                                              unsigned short* __restrict__ H,
                                              int nrows, const int* __restrict__ flags) {
  __shared__ char lds[65536];
  const int tid = threadIdx.x;
  const int wave = tid >> 6;
  const int lane = tid & 63;
  const int fm = lane & 15;
  const int fq = lane >> 4;
  const int isf = flags[0];
  const int m0 = blockIdx.x * 64;

  if (isf) {
#pragma unroll 4
    for (int j = 0; j < 16; ++j) {
      int r = wave * 16 + j;
      int grow = m0 + r; if (grow >= nrows) grow = nrows - 1;
      int c = lane ^ (j & 7);
      const float* gp = (const float*)X + (size_t)grow * FIN + c * 8;
      f32x4 lo = *(const f32x4*)gp;
      f32x4 hi = *(const f32x4*)(gp + 4);
      union { bf16x8 v; unsigned short u[8]; } cv;
#pragma unroll
      for (int k = 0; k < 4; k++) { cv.u[k] = f2b(lo[k]); cv.u[4 + k] = f2b(hi[k]); }
      *(bf16x8*)(lds + r * 1024 + lane * 16) = cv.v;
    }
  } else {
#pragma unroll
    for (int j = 0; j < 16; ++j) {
      int r = wave * 16 + j;
      int grow = m0 + r; if (grow >= nrows) grow = nrows - 1;
      int c = lane ^ (j & 7);
      const unsigned short* gp = (const unsigned short*)X + (size_t)grow * FIN + c * 8;
      __builtin_amdgcn_global_load_lds(
          (const __attribute__((address_space(1))) void*)gp,
          (__attribute__((address_space(3))) void*)(lds + r * 1024), 16, 0, 0);
    }
  }
  __syncthreads();

  f32x4 acc[4][4];
#pragma unroll
  for (int i = 0; i < 4; i++)
#pragma unroll
    for (int j = 0; j < 4; j++) acc[i][j] = (f32x4){0.f, 0.f, 0.f, 0.f};

  const unsigned short* wp[4];
#pragma unroll
  for (int i = 0; i < 4; i++)
    wp[i] = Wt + (size_t)((wave * 4 + i) * 16 + fm) * FIN + fq * 8;

  const int swz = fm & 7;
  bf16x8 bcur[4];
#pragma unroll
  for (int i = 0; i < 4; i++) bcur[i] = *(const bf16x8*)(wp[i]);

  for (int it = 0; it < 16; ++it) {
    int itn = (it + 1 < 16) ? it + 1 : 15;
    bf16x8 bnext[4];
#pragma unroll
    for (int i = 0; i < 4; i++) bnext[i] = *(const bf16x8*)(wp[i] + itn * 32);
    bf16x8 af[4];
#pragma unroll
    for (int mt = 0; mt < 4; mt++) {
      int slot = (it * 4 + fq) ^ swz;
      af[mt] = *(const bf16x8*)(lds + (mt * 16 + fm) * 1024 + slot * 16);
    }
#pragma unroll
    for (int mt = 0; mt < 4; mt++)
#pragma unroll
      for (int i = 0; i < 4; i++)
        acc[mt][i] = __builtin_amdgcn_mfma_f32_16x16x32_bf16(af[mt], bcur[i], acc[mt][i], 0, 0, 0);
#pragma unroll
    for (int i = 0; i < 4; i++) bcur[i] = bnext[i];
  }

#pragma unroll
  for (int i = 0; i < 4; i++) {
    int col = (wave * 4 + i) * 16 + fm;
    float bv = isf ? ((const float*)bias)[col] : b2f(((const unsigned short*)bias)[col]);
#pragma unroll
    for (int mt = 0; mt < 4; mt++) {
#pragma unroll
      for (int r = 0; r < 4; r++) {
        int row = m0 + mt * 16 + fq * 4 + r;
        if (row < nrows) H[(size_t)row * FOUT + col] = f2b(acc[mt][i][r] + bv);
      }
    }
  }
}

// ---- s1 = h@a_src, s2 = h@a_dst (fp32). One wave per row.
__global__ __launch_bounds__(256) void k_scores(const unsigned short* __restrict__ H,
                                                const void* __restrict__ a,
                                                float* __restrict__ s1, float* __restrict__ s2,
                                                int n, const int* __restrict__ flags) {
  int wave = threadIdx.x >> 6, lane = threadIdx.x & 63;
  int row = blockIdx.x * 4 + wave;
  if (row >= n) return;
  const ushort4* hp = (const ushort4*)(H + (size_t)row * FOUT);
  ushort4 hv = hp[lane];
  float as0, as1, as2, as3, ad0, ad1, ad2, ad3;
  if (flags[0]) {
    const float* af = (const float*)a;
    f32x4 s = *(const f32x4*)(af + lane * 4);
    f32x4 d = *(const f32x4*)(af + FOUT + lane * 4);
    as0 = s[0]; as1 = s[1]; as2 = s[2]; as3 = s[3];
    ad0 = d[0]; ad1 = d[1]; ad2 = d[2]; ad3 = d[3];
  } else {
    const ushort4* ap = (const ushort4*)a;
    ushort4 s = ap[lane], d = ap[64 + lane];
    as0 = b2f(s.x); as1 = b2f(s.y); as2 = b2f(s.z); as3 = b2f(s.w);
    ad0 = b2f(d.x); ad1 = b2f(d.y); ad2 = b2f(d.z); ad3 = b2f(d.w);
  }
  float h0 = b2f(hv.x), h1 = b2f(hv.y), h2 = b2f(hv.z), h3 = b2f(hv.w);
  float p1 = h0 * as0 + h1 * as1 + h2 * as2 + h3 * as3;
  float p2 = h0 * ad0 + h1 * ad1 + h2 * ad2 + h3 * ad3;
#pragma unroll
  for (int off = 32; off >= 1; off >>= 1) {
    p1 += __shfl_down(p1, off, 64);
    p2 += __shfl_down(p2, off, 64);
  }
  if (lane == 0) { s1[row] = p1; s2[row] = p2; }
}

// ==== CSR build: 2-level counting sort, no global atomics ====

// per-block bucket histogram -> C[blk*nbuck + b]
__global__ __launch_bounds__(256) void k_bcount(const int* __restrict__ e, int E, int chunk,
                                                int nbuck, int* __restrict__ C,
                                                const int* __restrict__ flags) {
  __shared__ int hist[512];
  int t = threadIdx.x, blk = blockIdx.x;
  for (int i = t; i < nbuck; i += 256) hist[i] = 0;
  __syncthreads();
  int lo = blk * chunk, hi = min(E, lo + chunk);
  bool i64 = flags[1] != 0;
  for (int i = lo + t; i < hi; i += 256) {
    int s = i64 ? ((const int2*)e)[i].x : e[i];
    atomicAdd(&hist[s >> BSHIFT], 1);
  }
  __syncthreads();
  for (int i = t; i < nbuck; i += 256) C[blk * nbuck + i] = hist[i];
}

// per bucket: exclusive scan over the 256 block counts -> O, total -> btot
__global__ __launch_bounds__(256) void k_bscanA(const int* __restrict__ C, int nbuck,
                                                int* __restrict__ O, int* __restrict__ btot) {
  int b = blockIdx.x, t = threadIdx.x;
  int lane = t & 63, w = t >> 6;
  int v = C[t * nbuck + b];
  int x = v;
#pragma unroll
  for (int off = 1; off < 64; off <<= 1) {
    int y = __shfl_up(x, off, 64);
    if (lane >= off) x += y;
  }
  __shared__ int ws[4];
  if (lane == 63) ws[w] = x;
  __syncthreads();
  int wbase = (w > 0 ? ws[0] : 0) + (w > 1 ? ws[1] : 0) + (w > 2 ? ws[2] : 0);
  O[t * nbuck + b] = x + wbase - v;
  if (t == 255) btot[b] = x + wbase;
}

// single block: exclusive scan of bucket totals -> bbase[0..nbuck], rowptr[N]=E
__global__ __launch_bounds__(512) void k_bscanB(const int* __restrict__ btot, int nbuck,
                                                int* __restrict__ bbase,
                                                int* __restrict__ rowptr, int N) {
  __shared__ int sh[512];
  int t = threadIdx.x;
  int v = (t < nbuck) ? btot[t] : 0;
  sh[t] = v;
  __syncthreads();
  for (int off = 1; off < 512; off <<= 1) {
    int u = (t >= off) ? sh[t - off] : 0;
    __syncthreads();
    sh[t] += u;
    __syncthreads();
  }
  if (t < nbuck) bbase[t] = sh[t] - v;
  if (t == nbuck - 1) { bbase[nbuck] = sh[t]; rowptr[N] = sh[t]; }
}

// re-read edges, write (src,dst) pairs into bucket-grouped stage.
// all of this block's writes go to its private per-bucket segments -> L2 merge.
__global__ __launch_bounds__(256) void k_bscatter(const int* __restrict__ e, int E, int chunk,
                                                  int nbuck, const int* __restrict__ O,
                                                  const int* __restrict__ bbase,
                                                  int2* __restrict__ stage,
                                                  const int* __restrict__ flags) {
  __shared__ int cur[512];
  int t = threadIdx.x, blk = blockIdx.x;
  for (int i = t; i < nbuck; i += 256) cur[i] = bbase[i] + O[blk * nbuck + i];
  __syncthreads();
  int lo = blk * chunk, hi = min(E, lo + chunk);
  bool i64 = flags[1] != 0;
  for (int i = lo + t; i < hi; i += 256) {
    int s, d;
    if (i64) { s = ((const int2*)e)[i].x; d = ((const int2*)e)[(size_t)E + i].x; }
    else     { s = e[i];                  d = e[E + i]; }
    int pos = atomicAdd(&cur[s >> BSHIFT], 1);
    stage[pos] = make_int2(s, d);
  }
}

// one block per bucket: LDS hist+scan of its 256 nodes -> rowptr slice,
// then LDS-cursor scatter of dst into the bucket's private csrd window.
__global__ __launch_bounds__(256) void k_fine(const int2* __restrict__ stage,
                                              const int* __restrict__ bbase,
                                              int* __restrict__ rowptr,
                                              int* __restrict__ csrd, int N) {
  __shared__ int hist[256];
  __shared__ int cursor[256];
  __shared__ int ws[4];
  int b = blockIdx.x, t = threadIdx.x;
  int s0 = b << BSHIFT;
  int base = bbase[b], end = bbase[b + 1], cnt = end - base;
  hist[t] = 0;
  __syncthreads();
  for (int i = t; i < cnt; i += 256) atomicAdd(&hist[stage[base + i].x - s0], 1);
  __syncthreads();
  int v = hist[t];
  int lane = t & 63, w = t >> 6;
  int x = v;
#pragma unroll
  for (int off = 1; off < 64; off <<= 1) {
    int y = __shfl_up(x, off, 64);
    if (lane >= off) x += y;
  }
  if (lane == 63) ws[w] = x;
  __syncthreads();
  int wbase = (w > 0 ? ws[0] : 0) + (w > 1 ? ws[1] : 0) + (w > 2 ? ws[2] : 0);
  int excl = x + wbase - v;
  cursor[t] = base + excl;
  if (s0 + t < N) rowptr[s0 + t] = base + excl;
  __syncthreads();
  for (int i = t; i < cnt; i += 256) {
    int2 p = stage[base + i];
    int pos = atomicAdd(&cursor[p.x - s0], 1);
    csrd[pos] = p.y;
  }
}

// ---- per-src-node gather. Half-wave pairing; 8 cols/lane.
__global__ __launch_bounds__(256) void k_gather(const unsigned short* __restrict__ H,
                                                const float* __restrict__ s1,
                                                const float* __restrict__ s2,
                                                const int* __restrict__ rowptr,
                                                const int* __restrict__ csrd,
                                                void* __restrict__ out, int n,
                                                const int* __restrict__ flags) {
  int wave = threadIdx.x >> 6, lane = threadIdx.x & 63;
  int row = blockIdx.x * 4 + wave;
  if (row >= n) return;
  int half = lane >> 5;
  int hl = lane & 31;
  int beg = rowptr[row], end = rowptr[row + 1];
  float s1v = s1[row];
  float ac[8];
#pragma unroll
  for (int k = 0; k < 8; k++) ac[k] = 0.f;
  float wsum = 0.f;

#pragma unroll 4
  for (int e = beg; e < end; e += 2) {
    int ei = e + half;
    int ee = (ei < end) ? ei : beg;
    int d = csrd[ee];
    float v = s1v + s2[d];
    v = v > 0.f ? v : 0.2f * v;
    float w = __expf(v);
    if (ei >= end) w = 0.f;
    union { u16x8 v; unsigned short u[8]; } hv;
    hv.v = *(const u16x8*)(H + (size_t)d * FOUT + hl * 8);
    wsum += w;
#pragma unroll
    for (int k = 0; k < 8; k++) ac[k] += w * b2f(hv.u[k]);
  }

#pragma unroll
  for (int k = 0; k < 8; k++) ac[k] += __shfl_down(ac[k], 32, 64);
  wsum += __shfl_down(wsum, 32, 64);

  if (half == 0) {
    float inv = 1.f / (wsum + 9e-15f);
    float o[8];
#pragma unroll
    for (int k = 0; k < 8; k++) {
      float x = ac[k] * inv;
      o[k] = x > 0.f ? x : __expf(x) - 1.f;
    }
    if (flags[0]) {
      float* op = (float*)out + (size_t)row * FOUT + hl * 8;
      *(f32x4*)op = (f32x4){o[0], o[1], o[2], o[3]};
      *(f32x4*)(op + 4) = (f32x4){o[4], o[5], o[6], o[7]};
    } else {
      union { u16x8 v; unsigned short u[8]; } ov;
#pragma unroll
      for (int k = 0; k < 8; k++) ov.u[k] = f2b(o[k]);
      *(u16x8*)((unsigned short*)out + (size_t)row * FOUT + hl * 8) = ov.v;
    }
  }
}

extern "C" void kernel_launch(void* const* d_in, const int* in_sizes, int n_in,
                              void* d_out, int out_size, void* d_ws, size_t ws_size,
                              hipStream_t stream) {
  const void* X = d_in[0];
  const int* edge = (const int*)d_in[1];
  const void* W = d_in[2];
  const void* A = d_in[3];
  const void* B = d_in[4];
  int N_ = in_sizes[0] / FIN;     // 100000
  int E_ = in_sizes[1] / 2;       // 3200000
  int nbuck = (N_ + 255) >> BSHIFT;        // 391
  int chunk = (E_ + NBLK - 1) / NBLK;      // 12500

  char* p = (char*)d_ws;
  auto alloc = [&](size_t bytes) {
    char* r = p; p += (bytes + 255) & ~(size_t)255; return r;
  };
  int* flags = (int*)alloc(256);
  unsigned short* H  = (unsigned short*)alloc((size_t)N_ * FOUT * 2);
  unsigned short* Wt = (unsigned short*)alloc((size_t)FIN * FOUT * 2);
  float* s1   = (float*)alloc((size_t)N_ * 4);
  float* s2   = (float*)alloc((size_t)N_ * 4);
  int* rowptr = (int*)alloc((size_t)(N_ + 1) * 4);
  int* csrd   = (int*)alloc((size_t)E_ * 4);
  int* C      = (int*)alloc((size_t)NBLK * nbuck * 4);
  int* O      = (int*)alloc((size_t)NBLK * nbuck * 4);
  int* btot   = (int*)alloc((size_t)nbuck * 4);
  int* bbase  = (int*)alloc((size_t)(nbuck + 1) * 4);
  int2* stage = (int2*)alloc((size_t)E_ * 8);

  k_probe<<<1, 256, 0, stream>>>((const unsigned short*)X, edge, flags);
  k_transpose<<<(FIN * FOUT) / 256, 256, 0, stream>>>(W, Wt, flags);
  k_gemm<<<(N_ + 63) / 64, 256, 0, stream>>>(X, Wt, B, H, N_, flags);
  k_scores<<<(N_ + 3) / 4, 256, 0, stream>>>(H, A, s1, s2, N_, flags);
  k_bcount<<<NBLK, 256, 0, stream>>>(edge, E_, chunk, nbuck, C, flags);
  k_bscanA<<<nbuck, 256, 0, stream>>>(C, nbuck, O, btot);
  k_bscanB<<<1, 512, 0, stream>>>(btot, nbuck, bbase, rowptr, N_);
  k_bscatter<<<NBLK, 256, 0, stream>>>(edge, E_, chunk, nbuck, O, bbase, stage, flags);
  k_fine<<<nbuck, 256, 0, stream>>>(stage, bbase, rowptr, csrd, N_);
  k_gather<<<(N_ + 3) / 4, 256, 0, stream>>>(H, s1, s2, rowptr, csrd,
                                             d_out, N_, flags);
}